// Round 1
// baseline (140.133 us; speedup 1.0000x reference)
//
#include <hip/hip_runtime.h>
#include <math.h>

#define B_ 16
#define N_ 4096
#define K_ 16
#define ALPHA_ 1.05f

#define JSPLIT 8            // j-chunks per point (one wave each)
#define CHUNK (N_ / JSPLIT) // 512 j's per wave
#define TJ 256              // j-tile staged in LDS per wave
#define PTS 128             // points per block (TWO per lane)
#define BLK 512             // 8 waves
#define SENT_F 60000.0f     // sentinel > any real sq-dist (~300); f16-representable

typedef __fp16 h2 __attribute__((ext_vector_type(2)));

struct H2x4 { h2 v[4]; };   // view of one float4 = 8 fp16 = 4 h2 pairs

// ---------------------------------------------------------------------------
// Guaranteed-packed f16 ops via inline asm (VOP3P). Compiler was scalarizing
// the __builtin_elementwise path (~3x instr bloat, earlier counters).
// ---------------------------------------------------------------------------
__device__ __forceinline__ h2 h2min(h2 a, h2 b) {
    unsigned int ua = __builtin_bit_cast(unsigned int, a);
    unsigned int ub = __builtin_bit_cast(unsigned int, b);
    unsigned int r;
    asm("v_pk_min_f16 %0, %1, %2" : "=v"(r) : "v"(ua), "v"(ub));
    return __builtin_bit_cast(h2, r);
}
__device__ __forceinline__ h2 h2max(h2 a, h2 b) {
    unsigned int ua = __builtin_bit_cast(unsigned int, a);
    unsigned int ub = __builtin_bit_cast(unsigned int, b);
    unsigned int r;
    asm("v_pk_max_f16 %0, %1, %2" : "=v"(r) : "v"(ua), "v"(ub));
    return __builtin_bit_cast(h2, r);
}
__device__ __forceinline__ h2 h2add(h2 a, h2 b) {
    unsigned int ua = __builtin_bit_cast(unsigned int, a);
    unsigned int ub = __builtin_bit_cast(unsigned int, b);
    unsigned int r;
    asm("v_pk_add_f16 %0, %1, %2" : "=v"(r) : "v"(ua), "v"(ub));
    return __builtin_bit_cast(h2, r);
}
__device__ __forceinline__ h2 h2mul(h2 a, h2 b) {
    unsigned int ua = __builtin_bit_cast(unsigned int, a);
    unsigned int ub = __builtin_bit_cast(unsigned int, b);
    unsigned int r;
    asm("v_pk_mul_f16 %0, %1, %2" : "=v"(r) : "v"(ua), "v"(ub));
    return __builtin_bit_cast(h2, r);
}
__device__ __forceinline__ h2 h2fma(h2 a, h2 b, h2 c) {
    unsigned int ua = __builtin_bit_cast(unsigned int, a);
    unsigned int ub = __builtin_bit_cast(unsigned int, b);
    unsigned int uc = __builtin_bit_cast(unsigned int, c);
    unsigned int r;
    asm("v_pk_fma_f16 %0, %1, %2, %3" : "=v"(r) : "v"(ua), "v"(ub), "v"(uc));
    return __builtin_bit_cast(h2, r);
}

// ---------------------------------------------------------------------------
// Batcher odd-even merge sort, n=16, ascending, TWO independent streams
// interleaved (point A and point B) so the scheduler always has a second
// dependency chain to issue into. 63 CE x 2 arrays.
// ---------------------------------------------------------------------------
__device__ __forceinline__ void oems_sort16h_x2(h2 va[16], h2 vb[16]) {
#pragma unroll
    for (int p = 1; p < 16; p <<= 1) {
#pragma unroll
        for (int k = p; k >= 1; k >>= 1) {
#pragma unroll
            for (int j = k & (p - 1); j + k < 16; j += 2 * k) {
#pragma unroll
                for (int i = 0; i < k; ++i) {
                    if (i + j + k < 16 &&
                        ((i + j) / (2 * p)) == ((i + j + k) / (2 * p))) {
                        {
                            const h2 a = va[i + j], c = va[i + j + k];
                            va[i + j]     = h2min(a, c);
                            va[i + j + k] = h2max(a, c);
                        }
                        {
                            const h2 a = vb[i + j], c = vb[i + j + k];
                            vb[i + j]     = h2min(a, c);
                            vb[i + j + k] = h2max(a, c);
                        }
                    }
                }
            }
        }
    }
}

// knn := lowest 16 of {knn, c} per half-stream; both sorted asc. Two points.
__device__ __forceinline__ void merge16h_x2(h2 ka[16], const h2 ca[16],
                                            h2 kb[16], const h2 cb[16]) {
#pragma unroll
    for (int i = 0; i < 16; ++i) {
        ka[i] = h2min(ka[i], ca[15 - i]);
        kb[i] = h2min(kb[i], cb[15 - i]);
    }
#pragma unroll
    for (int j = 8; j > 0; j >>= 1) {
#pragma unroll
        for (int i = 0; i < 16; ++i) {
            const int l = i ^ j;
            if (l > i) {
                {
                    const h2 a = ka[i], c = ka[l];
                    ka[i] = h2min(a, c);
                    ka[l] = h2max(a, c);
                }
                {
                    const h2 a = kb[i], c = kb[l];
                    kb[i] = h2min(a, c);
                    kb[l] = h2max(a, c);
                }
            }
        }
    }
}

// f32 merge for the once-per-wave lo/hi combine (both sorted asc).
__device__ __forceinline__ void merge16f(float knn[16], const float c[16]) {
#pragma unroll
    for (int i = 0; i < 16; ++i) knn[i] = fminf(knn[i], c[15 - i]);
#pragma unroll
    for (int j = 8; j > 0; j >>= 1) {
#pragma unroll
        for (int i = 0; i < 16; ++i) {
            const int l = i ^ j;
            if (l > i) {
                const float a = knn[i], b = knn[l];
                knn[i] = fminf(a, b);
                knn[l] = fmaxf(a, b);
            }
        }
    }
}

// ---------------------------------------------------------------------------
// Process one 256-j f16-SoA tile (coords stored NEGATED) for TWO query
// points per lane: every broadcast ds_read_b128 is amortized over both.
// ---------------------------------------------------------------------------
template <bool HAS_SELF>
__device__ __forceinline__ void process_tile2(const float4* __restrict__ xs4,
                                              const float4* __restrict__ ys4,
                                              const float4* __restrict__ zs4,
                                              int jg0, int ia, int ib,
                                              h2 qax, h2 qay, h2 qaz,
                                              h2 qbx, h2 qby, h2 qbz,
                                              h2 knnA[16], h2 knnB[16]) {
#pragma unroll 1
    for (int bb = 0; bb < TJ / 32; ++bb) {
        h2 cA[16], cB[16];
#pragma unroll
        for (int r = 0; r < 4; ++r) {
            const H2x4 hx = __builtin_bit_cast(H2x4, xs4[bb * 4 + r]); // b128 broadcast
            const H2x4 hy = __builtin_bit_cast(H2x4, ys4[bb * 4 + r]);
            const H2x4 hz = __builtin_bit_cast(H2x4, zs4[bb * 4 + r]);
#pragma unroll
            for (int t = 0; t < 4; ++t) {
                const h2 dxA = h2add(qax, hx.v[t]);
                const h2 dyA = h2add(qay, hy.v[t]);
                const h2 dzA = h2add(qaz, hz.v[t]);
                h2 dA = h2mul(dxA, dxA);
                dA = h2fma(dyA, dyA, dA);
                dA = h2fma(dzA, dzA, dA);
                const h2 dxB = h2add(qbx, hx.v[t]);
                const h2 dyB = h2add(qby, hy.v[t]);
                const h2 dzB = h2add(qbz, hz.v[t]);
                h2 dB = h2mul(dxB, dxB);
                dB = h2fma(dyB, dyB, dB);
                dB = h2fma(dzB, dzB, dB);
                if (HAS_SELF) {
                    const int j0 = jg0 + bb * 32 + r * 8 + 2 * t;
                    if (j0 == ia)     dA.x = (__fp16)SENT_F;
                    if (j0 + 1 == ia) dA.y = (__fp16)SENT_F;
                    if (j0 == ib)     dB.x = (__fp16)SENT_F;
                    if (j0 + 1 == ib) dB.y = (__fp16)SENT_F;
                }
                cA[r * 4 + t] = dA;
                cB[r * 4 + t] = dB;
            }
        }
        oems_sort16h_x2(cA, cB);
        merge16h_x2(knnA, cA, knnB, cB);
    }
}

// ---------------------------------------------------------------------------
// Kernel 1: per-point mean of 16 smallest non-self squared distances.
// Block = 512 threads = 8 waves, covering 128 points (2 per lane:
// i0+lane and i0+64+lane). Wave w handles j-chunk w (512 j's). Candidates
// staged in LDS as negated f16 SoA pairs; every tile read serves 2 points.
// ---------------------------------------------------------------------------
__global__ __launch_bounds__(BLK, 4) void knn_kernel(const float* __restrict__ pcs,
                                                     float* __restrict__ knn_out,
                                                     float* __restrict__ out) {
    __shared__ float4 s[JSPLIT][3][TJ / 8];        // f16 SoA x/y/z, 12 KB
    __shared__ __fp16 lst[JSPLIT][PTS][K_ + 1];    // 34.8 KB (values f16-exact)

    if (blockIdx.x == 0 && threadIdx.x == 0) out[0] = 0.0f; // replaces memset dispatch

    const int b    = blockIdx.x >> 5;              // 32 blocks per batch
    const int grp  = blockIdx.x & 31;
    const int i0   = grp * PTS;                    // 128-aligned
    const int lane = threadIdx.x & 63;
    const int w    = threadIdx.x >> 6;

    const float* __restrict__ src = pcs + (size_t)b * N_ * 3;

    const int ia = i0 + lane;
    const int ib = i0 + 64 + lane;
    const __fp16 qaxh = (__fp16)src[3 * ia + 0];   // RTN, same grid as candidates
    const __fp16 qayh = (__fp16)src[3 * ia + 1];
    const __fp16 qazh = (__fp16)src[3 * ia + 2];
    const __fp16 qbxh = (__fp16)src[3 * ib + 0];
    const __fp16 qbyh = (__fp16)src[3 * ib + 1];
    const __fp16 qbzh = (__fp16)src[3 * ib + 2];
    const h2 qax = {qaxh, qaxh}, qay = {qayh, qayh}, qaz = {qazh, qazh};
    const h2 qbx = {qbxh, qbxh}, qby = {qbyh, qbyh}, qbz = {qbzh, qbzh};

    const h2 sent = {(__fp16)SENT_F, (__fp16)SENT_F};
    h2 knnA[K_], knnB[K_];
#pragma unroll
    for (int t = 0; t < K_; ++t) { knnA[t] = sent; knnB[t] = sent; }

    const int jbase = w * CHUNK;
    h2* sxw = (h2*)&s[w][0][0];
    h2* syw = (h2*)&s[w][1][0];
    h2* szw = (h2*)&s[w][2][0];

#pragma unroll 1
    for (int t0 = 0; t0 < CHUNK; t0 += TJ) {
        // ---- stage: lane l loads 4 points (3 float4 = 12 floats), converts
        //      NEGATED (RTN) to f16, writes paired h2 SoA.
        const float4* __restrict__ g4 =
            (const float4*)(src + (size_t)(jbase + t0) * 3);
        const float4 f0 = g4[3 * lane + 0];
        const float4 f1 = g4[3 * lane + 1];
        const float4 f2 = g4[3 * lane + 2];
        sxw[2 * lane + 0] = h2{(__fp16)(-f0.x), (__fp16)(-f0.w)};
        sxw[2 * lane + 1] = h2{(__fp16)(-f1.z), (__fp16)(-f2.y)};
        syw[2 * lane + 0] = h2{(__fp16)(-f0.y), (__fp16)(-f1.x)};
        syw[2 * lane + 1] = h2{(__fp16)(-f1.w), (__fp16)(-f2.z)};
        szw[2 * lane + 0] = h2{(__fp16)(-f0.z), (__fp16)(-f1.y)};
        szw[2 * lane + 1] = h2{(__fp16)(-f2.x), (__fp16)(-f2.w)};
        // wave-private quadrant; lanes lockstep within the wave, compiler
        // inserts lgkmcnt waits for the write->read dependence.

        const int jg0 = jbase + t0;
        // block's 128 points lie in one 256-window -> single check covers ia,ib
        if ((i0 >> 8) == (jg0 >> 8)) {
            process_tile2<true >(&s[w][0][0], &s[w][1][0], &s[w][2][0],
                                 jg0, ia, ib, qax, qay, qaz, qbx, qby, qbz,
                                 knnA, knnB);
        } else {
            process_tile2<false>(&s[w][0][0], &s[w][1][0], &s[w][2][0],
                                 jg0, ia, ib, qax, qay, qaz, qbx, qby, qbz,
                                 knnA, knnB);
        }
    }

    // ---- combine the two packed streams (lo/hi) for each point, once per wave
    {
        float lo[K_], hi[K_];
#pragma unroll
        for (int t = 0; t < K_; ++t) { lo[t] = (float)knnA[t].x; hi[t] = (float)knnA[t].y; }
        merge16f(lo, hi);   // lowest 16 of 32, sorted asc
#pragma unroll
        for (int q = 0; q < K_; ++q) lst[w][lane][q] = (__fp16)lo[q];
        lst[w][lane][K_] = (__fp16)SENT_F;
    }
    {
        float lo[K_], hi[K_];
#pragma unroll
        for (int t = 0; t < K_; ++t) { lo[t] = (float)knnB[t].x; hi[t] = (float)knnB[t].y; }
        merge16f(lo, hi);
#pragma unroll
        for (int q = 0; q < K_; ++q) lst[w][64 + lane][q] = (__fp16)lo[q];
        lst[w][64 + lane][K_] = (__fp16)SENT_F;
    }
    __syncthreads();

    // ---- 8-way merge of sorted lists, one thread per point (waves 0-1)
    if (threadIdx.x < PTS) {
        const int l = threadIdx.x;
        int p0 = 0, p1 = 0, p2 = 0, p3 = 0, p4 = 0, p5 = 0, p6 = 0, p7 = 0;
        float e0 = (float)lst[0][l][0], e1 = (float)lst[1][l][0];
        float e2 = (float)lst[2][l][0], e3 = (float)lst[3][l][0];
        float e4 = (float)lst[4][l][0], e5 = (float)lst[5][l][0];
        float e6 = (float)lst[6][l][0], e7 = (float)lst[7][l][0];
        float sm = 0.0f;
#pragma unroll
        for (int step = 0; step < K_; ++step) {
            const float m01 = fminf(e0, e1), m23 = fminf(e2, e3);
            const float m45 = fminf(e4, e5), m67 = fminf(e6, e7);
            const float m = fminf(fminf(m01, m23), fminf(m45, m67));
            sm += m;
            if (e0 == m)      { e0 = (float)lst[0][l][++p0]; }
            else if (e1 == m) { e1 = (float)lst[1][l][++p1]; }
            else if (e2 == m) { e2 = (float)lst[2][l][++p2]; }
            else if (e3 == m) { e3 = (float)lst[3][l][++p3]; }
            else if (e4 == m) { e4 = (float)lst[4][l][++p4]; }
            else if (e5 == m) { e5 = (float)lst[5][l][++p5]; }
            else if (e6 == m) { e6 = (float)lst[6][l][++p6]; }
            else              { e7 = (float)lst[7][l][++p7]; }
        }
        knn_out[b * N_ + i0 + l] = sm * (1.0f / (float)K_);
    }
}

// ---------------------------------------------------------------------------
// Block reduction helper (256 threads = 4 waves)
// ---------------------------------------------------------------------------
__device__ __forceinline__ float block_reduce_sum_256(float v, float* sbuf) {
    const int lane = threadIdx.x & 63;
    const int w    = threadIdx.x >> 6;
#pragma unroll
    for (int o = 32; o > 0; o >>= 1) v += __shfl_down(v, o, 64);
    __syncthreads();
    if (lane == 0) sbuf[w] = v;
    __syncthreads();
    return sbuf[0] + sbuf[1] + sbuf[2] + sbuf[3];
}

// ---------------------------------------------------------------------------
// Kernel 2: per-batch mean, std (two-pass), threshold, penalty partial sum,
// fused final: atomicAdd of scaled penalty into out[0] (zeroed by knn_kernel).
// ---------------------------------------------------------------------------
__global__ __launch_bounds__(256) void stats_kernel(const float* __restrict__ knn_d,
                                                    float* __restrict__ out) {
    const int b   = blockIdx.x;
    const int tid = threadIdx.x;
    const float* __restrict__ x = knn_d + (size_t)b * N_;

    __shared__ float sbuf[4];

    float v[16];
    float s = 0.0f;
#pragma unroll
    for (int t = 0; t < 16; ++t) {
        v[t] = x[tid + t * 256];
        s += v[t];
    }
    const float total = block_reduce_sum_256(s, sbuf);
    const float mu = total * (1.0f / (float)N_);

    float vs = 0.0f;
#pragma unroll
    for (int t = 0; t < 16; ++t) {
        const float d = v[t] - mu;
        vs += d * d;
    }
    const float var    = block_reduce_sum_256(vs, sbuf) * (1.0f / (float)N_);
    const float thresh = mu + ALPHA_ * sqrtf(var);

    float p = 0.0f;
#pragma unroll
    for (int t = 0; t < 16; ++t) {
        if (v[t] > thresh) p += v[t];
    }
    const float psum = block_reduce_sum_256(p, sbuf);
    if (tid == 0) atomicAdd(out, psum * (1.0f / (float)(B_ * N_)));
}

extern "C" void kernel_launch(void* const* d_in, const int* in_sizes, int n_in,
                              void* d_out, int out_size, void* d_ws, size_t ws_size,
                              hipStream_t stream) {
    const float* pcs = (const float*)d_in[0];
    float* out = (float*)d_out;

    float* knn_d = (float*)d_ws;             // B*N floats = 256 KB

    knn_kernel<<<B_ * (N_ / PTS), BLK, 0, stream>>>(pcs, knn_d, out);
    stats_kernel<<<B_, 256, 0, stream>>>(knn_d, out);
}